// Round 11
// baseline (1768.687 us; speedup 1.0000x reference)
//
#include <hip/hip_runtime.h>
#include <hip/hip_bf16.h>
#include <stdint.h>

#define B_  4096
#define D_  1024
#define NS_ 16000
#define C_  1000
#define H_  256
#define LBLK 4000    // label-extraction blocks (4 waves/block, after conversions)
#define QCB  1024    // q conversion blocks   (1024*1024 float4 = exact)
#define KCB  4000    // keys conversion blocks (4000*1024 float4 = exact)
#define FCB  64      // fc1 conversion blocks  (64*1024 float4 = exact)
#define CONVB (QCB + KCB + FCB)
#define RSTRIDE 2048 // padded run stride (R = 125 tiles * 16 slots = 2000)

typedef __attribute__((ext_vector_type(8))) short bf16x8;
typedef __attribute__((ext_vector_type(4))) float f32x4;
typedef __attribute__((ext_vector_type(16))) float f32x16;
typedef __attribute__((ext_vector_type(8))) int i32x8;

__device__ __forceinline__ unsigned short f2bf(float f) {
  union { float f; unsigned u; } v; v.f = f;
  unsigned u = v.u;
  u += 0x7FFF + ((u >> 16) & 1);   // round-to-nearest-even
  return (unsigned short)(u >> 16);
}

__device__ __forceinline__ float bf2f(unsigned short h) {
  union { unsigned u; float f; } v; v.u = ((unsigned)h) << 16;
  return v.f;
}

// ---------------- fused prep: fp32 -> bf16/fp8 conversion (first), labels (last) ----
__global__ void prep_kernel(const float4* __restrict__ q, const float4* __restrict__ keys,
                            const float4* __restrict__ fc1, const float* __restrict__ values,
                            ushort4* __restrict__ qb, int* __restrict__ q8,
                            int* __restrict__ keys8, ushort4* __restrict__ fc1b,
                            int* __restrict__ labels) {
  const int bid = blockIdx.x;
  if (bid < QCB) {                                   // q -> qb (bf16) + q8 (fp8 x64)
    const size_t i0 = (size_t)bid * 1024 + threadIdx.x;
    #pragma unroll
    for (int k = 0; k < 4; ++k) {
      const size_t i = i0 + k * 256;
      float4 v = q[i];
      ushort4 r; r.x = f2bf(v.x); r.y = f2bf(v.y); r.z = f2bf(v.z); r.w = f2bf(v.w);
      qb[i] = r;
      int p = __builtin_amdgcn_cvt_pk_fp8_f32(v.x * 64.f, v.y * 64.f, 0, false);
      p     = __builtin_amdgcn_cvt_pk_fp8_f32(v.z * 64.f, v.w * 64.f, p, true);
      q8[i] = p;
    }
    return;
  }
  if (bid < QCB + KCB) {                             // keys -> keys8 (fp8 x64)
    const size_t i0 = (size_t)(bid - QCB) * 1024 + threadIdx.x;
    #pragma unroll
    for (int k = 0; k < 4; ++k) {
      const size_t i = i0 + k * 256;
      float4 v = keys[i];
      int p = __builtin_amdgcn_cvt_pk_fp8_f32(v.x * 64.f, v.y * 64.f, 0, false);
      p     = __builtin_amdgcn_cvt_pk_fp8_f32(v.z * 64.f, v.w * 64.f, p, true);
      keys8[i] = p;
    }
    return;
  }
  if (bid < CONVB) {                                 // fc1 -> fc1b (bf16)
    const size_t i0 = (size_t)(bid - QCB - KCB) * 1024 + threadIdx.x;
    #pragma unroll
    for (int k = 0; k < 4; ++k) {
      const size_t i = i0 + k * 256;
      float4 v = fc1[i];
      ushort4 r; r.x = f2bf(v.x); r.y = f2bf(v.y); r.z = f2bf(v.z); r.w = f2bf(v.w);
      fc1b[i] = r;
    }
    return;
  }
  // label extraction: wave per support row, early exit on one-hot hit
  const int s = (bid - CONVB) * 4 + (threadIdx.x >> 6);
  const int lane = threadIdx.x & 63;
  const float4* row = (const float4*)(values + (size_t)s * C_);
  int lab = -1;
  for (int j = lane; j < C_ / 4; j += 64) {
    float4 v = row[j];
    if (v.x > 0.5f) lab = j * 4 + 0;
    if (v.y > 0.5f) lab = j * 4 + 1;
    if (v.z > 0.5f) lab = j * 4 + 2;
    if (v.w > 0.5f) lab = j * 4 + 3;
    if (__ballot(lab >= 0)) break;     // one-hot: whole wave exits once found
  }
  if (lab >= 0) labels[s] = lab;
}

// ---------------- midpipe: gemmgate (blocks 0..127) ∥ sortpipe (block 128) ----------
// sortpipe builds hist from labels via LDS atomics (no memset / global hist).
union MidShared {
  struct {
    short As[32 * 64];                 //  4 KB
    short Bs[256 * 64];                // 32 KB
    float gred[4][32][2];              //  1 KB
  } g;
  struct {
    int sscan[1024];                   //  4 KB
    int sboff[C_ + 1];
    int scnt[C_];
    unsigned short slab[NS_];          // 32 KB
    int stile[NS_ / 128];
  } s;
};

__global__ __launch_bounds__(1024) void midpipe_kernel(
    const short* __restrict__ A, const short* __restrict__ Bm,
    const float* __restrict__ bias, const float* __restrict__ fc2_w,
    const float* __restrict__ fc2_b, float* __restrict__ ab,
    const int* __restrict__ labels,
    int* __restrict__ sortidx, int* __restrict__ runid, int* __restrict__ labstart)
{
  __shared__ MidShared u;
  const int tid = threadIdx.x;

  if (blockIdx.x < B_ / 32) {
    // ---- gemmgate: fused fc1 GEMM + gate, threads 0..255 active ----
    short* As = u.g.As;
    short* Bs = u.g.Bs;
    const bool act = tid < 256;
    const int wave = (tid >> 6) & 3, lane = tid & 63;
    const int quad = lane >> 4, l16 = lane & 15;
    const int wn = wave;                      // wave owns cols wn*64..+63
    const int rstart = blockIdx.x * 32;

    f32x4 acc[2][4];
    #pragma unroll
    for (int i = 0; i < 2; ++i)
      #pragma unroll
      for (int j = 0; j < 4; ++j) acc[i][j] = (f32x4)0.f;

    const int r_  = (lane >> 3);             // 0..7 (row within 8-row chunk)
    const int kc_ = ((lane & 7) ^ r_) * 8;   // swizzled 16B k-chunk element offset

    for (int kt = 0; kt < D_; kt += 64) {
      __syncthreads();
      if (act) {
        {   // A: 32 rows = 4 groups of 1KB, one per wave
          const int row = wave * 8 + r_;
          const short* gA = A + (size_t)(rstart + row) * D_ + kt + kc_;
          __builtin_amdgcn_global_load_lds(
              (const __attribute__((address_space(1))) void*)gA,
              (__attribute__((address_space(3))) void*)(As + wave * 512), 16, 0, 0);
        }
        #pragma unroll
        for (int i = 0; i < 8; ++i) {        // B: 256 rows = 32 groups
          const int g = i * 4 + wave;
          const int row = g * 8 + r_;
          const short* gB = Bm + (size_t)row * D_ + kt + kc_;
          __builtin_amdgcn_global_load_lds(
              (const __attribute__((address_space(1))) void*)gB,
              (__attribute__((address_space(3))) void*)(Bs + g * 512), 16, 0, 0);
        }
      }
      __syncthreads();
      if (act) {
        #pragma unroll
        for (int ks = 0; ks < 64; ks += 32) {
          bf16x8 af[2], bfr[4];
          const int kb = (ks >> 3) + quad;
          #pragma unroll
          for (int mt = 0; mt < 2; ++mt) {
            const int row = mt * 16 + l16;
            af[mt] = *(const bf16x8*)(As + row * 64 + ((kb ^ (row & 7)) << 3));
          }
          #pragma unroll
          for (int nt = 0; nt < 4; ++nt) {
            const int row = wn * 64 + nt * 16 + l16;
            bfr[nt] = *(const bf16x8*)(Bs + row * 64 + ((kb ^ (row & 7)) << 3));
          }
          #pragma unroll
          for (int mt = 0; mt < 2; ++mt)
            #pragma unroll
            for (int nt = 0; nt < 4; ++nt)
              acc[mt][nt] = __builtin_amdgcn_mfma_f32_16x16x32_bf16(af[mt], bfr[nt], acc[mt][nt], 0, 0, 0);
        }
      }
    }

    if (act) {
      // gate partials: g = sum_col relu(acc+bias)*fc2_w[.,col]
      float g0p[2][4], g1p[2][4];
      #pragma unroll
      for (int mt = 0; mt < 2; ++mt)
        #pragma unroll
        for (int r = 0; r < 4; ++r) { g0p[mt][r] = 0.f; g1p[mt][r] = 0.f; }
      #pragma unroll
      for (int nt = 0; nt < 4; ++nt) {
        const int col = wn * 64 + nt * 16 + l16;
        const float bv = bias[col];
        const float w0 = fc2_w[col], w1 = fc2_w[H_ + col];
        #pragma unroll
        for (int mt = 0; mt < 2; ++mt)
          #pragma unroll
          for (int r = 0; r < 4; ++r) {
            float xv = acc[mt][nt][r] + bv;
            xv = xv > 0.f ? xv : 0.f;
            g0p[mt][r] += xv * w0;
            g1p[mt][r] += xv * w1;
          }
      }
      #pragma unroll
      for (int mt = 0; mt < 2; ++mt)
        #pragma unroll
        for (int r = 0; r < 4; ++r) {
          float a0 = g0p[mt][r], a1 = g1p[mt][r];
          #pragma unroll
          for (int off = 8; off > 0; off >>= 1) {   // reduce over l16 within quad
            a0 += __shfl_xor(a0, off);
            a1 += __shfl_xor(a1, off);
          }
          if (l16 == 0) {
            const int row = mt * 16 + quad * 4 + r;
            u.g.gred[wave][row][0] = a0;
            u.g.gred[wave][row][1] = a1;
          }
        }
    }
    __syncthreads();
    if (tid < 32) {
      float g0 = u.g.gred[0][tid][0] + u.g.gred[1][tid][0] + u.g.gred[2][tid][0] +
                 u.g.gred[3][tid][0] + fc2_b[0];
      float g1 = u.g.gred[0][tid][1] + u.g.gred[1][tid][1] + u.g.gred[2][tid][1] +
                 u.g.gred[3][tid][1] + fc2_b[1];
      ab[rstart + tid]      = 1.f / (1.f + __expf(-g0));                              // alpha
      ab[B_ + rstart + tid] = fmaxf(g1, 0.f) + log1pf(__expf(-fabsf(g1))) + 0.001f;   // beta
    }
    return;
  }

  // ---- sortpipe: hist + scan + scatter + runid + labstart (1 block, 1024 thr) ----
  const int t = tid;
  if (t < C_) u.s.scnt[t] = 0;
  __syncthreads();
  for (int s = t; s < NS_; s += 1024)
    atomicAdd(&u.s.scnt[labels[s]], 1);              // hist via LDS atomics
  __syncthreads();
  int v = (t < C_) ? u.s.scnt[t] : 0;
  u.s.sscan[t] = v;
  __syncthreads();
  if (t < C_) u.s.scnt[t] = 0;                       // re-zero for scatter
  for (int off = 1; off < 1024; off <<= 1) {
    int w = (t >= off) ? u.s.sscan[t - off] : 0;
    __syncthreads(); u.s.sscan[t] += w; __syncthreads();
  }
  if (t == 0) u.s.sboff[0] = 0;
  if (t < C_) u.s.sboff[t + 1] = u.s.sscan[t];
  __syncthreads();

  for (int s = t; s < NS_; s += 1024) {
    const int lab = labels[s];
    const int pos = u.s.sboff[lab] + atomicAdd(&u.s.scnt[lab], 1);
    sortidx[pos] = s;
    u.s.slab[pos] = (unsigned short)lab;
  }
  __syncthreads();

  // runid: slot = (c>>7)*16 + label-rank-within-tile (rank < 16 whp)
  const int c0 = t * 16;
  int flags[16]; int cnt = 0;
  if (c0 < NS_) {
    int prev = (c0 == 0) ? u.s.slab[0] : u.s.slab[c0 - 1];
    #pragma unroll
    for (int i = 0; i < 16; ++i) {
      const int l = u.s.slab[c0 + i];
      const int f = ((c0 + i) != 0) && (l != prev);
      flags[i] = f; cnt += f; prev = l;
    }
  }
  u.s.sscan[t] = cnt; __syncthreads();
  for (int off = 1; off < 1024; off <<= 1) {
    int w = (t >= off) ? u.s.sscan[t - off] : 0;
    __syncthreads(); u.s.sscan[t] += w; __syncthreads();
  }
  if (c0 < NS_ && (t & 7) == 0) u.s.stile[t >> 3] = (u.s.sscan[t] - cnt) + flags[0];
  __syncthreads();
  if (c0 < NS_) {
    int run = u.s.sscan[t] - cnt;
    const int base = (c0 >> 7) * 16 - u.s.stile[c0 >> 7];
    #pragma unroll
    for (int i = 0; i < 16; ++i) {
      run += flags[i];
      runid[c0 + i] = base + run;
    }
  }
  if (t == 0) runid[NS_] = (NS_ >> 7) * 16;   // 2000
  __threadfence();
  __syncthreads();
  if (t <= C_) labstart[t] = runid[u.s.sboff[t]];
}

// ---------------- MX-fp8 128x128 GEMM + exp + MFMA label-sum + last-block reduce ----
// r8/r10-proven K-loop and epilogues; NEW epilogue 3: after partials stores, each
// block release-fences and bumps done[rstart-group]; the 125th (last) block per
// rstart acquire-fences and reduces its 128 rows (partials -> out with z fusion),
// overlapped with other rstarts' remaining tiles. Device-scope fences per G12/G16.
__device__ __forceinline__ i32x8 mx_frag(const char* base, int lrow, int kh, int sel) {
  const int c0 = kh * 4 + sel * 2;
  const int s = lrow & 7;
  const int4 lo = *(const int4*)(base + lrow * 128 + (((c0    ) ^ s) << 4));
  const int4 hi = *(const int4*)(base + lrow * 128 + (((c0 + 1) ^ s) << 4));
  i32x8 f;
  f[0] = lo.x; f[1] = lo.y; f[2] = lo.z; f[3] = lo.w;
  f[4] = hi.x; f[5] = hi.y; f[6] = hi.z; f[7] = hi.w;
  return f;
}

__global__ __launch_bounds__(256, 4) void mxgemm_kernel(
    const char* __restrict__ A8, const char* __restrict__ B8,
    const float* __restrict__ beta, float* __restrict__ partials,
    const int* __restrict__ sortidx, const int* __restrict__ runid,
    const int* __restrict__ labstart, const float* __restrict__ z,
    const float* __restrict__ ps, float* __restrict__ out, int* __restrict__ done)
{
  __shared__ __align__(16) char smem[32768];   // As|Bs in K-loop; bf16 tile in epilogue
  __shared__ float sbeta[128];
  __shared__ __align__(16) unsigned short Es[16 * 136];  // E[slot][k], stride 136
  __shared__ int islast;
  char* As = smem;
  char* Bs = smem + 16384;

  const int tid  = threadIdx.x;
  const int wave = tid >> 6, lane = tid & 63;
  const int sel  = lane >> 5, l32 = lane & 31;
  const int wm = wave >> 1, wn = wave & 1;     // 2x2 wave grid, 64x64 per wave
  const int rstart = blockIdx.x * 128;         // x fastest: blocks share nstart window
  const int nstart = blockIdx.y * 128;

  // build E: zero, then one-hot 1.0 at (slot = local label rank, k = col-in-tile)
  for (int i = tid; i < (16 * 136) / 2; i += 256) ((int*)Es)[i] = 0;
  if (tid < 128) sbeta[tid] = beta[rstart + tid];
  __syncthreads();
  if (tid < 128) Es[(runid[nstart + tid] & 15) * 136 + tid] = 0x3F80;  // 1.0 bf16

  // staging geometry: slot s = wave*256 + i*64 + lane; row = s>>3, chunk c = s&7
  const int srow_ = (lane >> 3);           // row offset within 8-row group
  const int gch_  = (lane & 7) ^ srow_;    // swizzled source chunk (row&7 == lane>>3)

  int arow[4], brow[4];
  #pragma unroll
  for (int i = 0; i < 4; ++i) {
    const int row = wave * 32 + i * 8 + srow_;
    arow[i] = rstart + row;
    brow[i] = sortidx[nstart + row];
  }

  f32x16 acc[2][2];
  #pragma unroll
  for (int i = 0; i < 2; ++i)
    #pragma unroll
    for (int j = 0; j < 2; ++j) acc[i][j] = (f32x16)0.f;

  for (int kt = 0; kt < D_; kt += 128) {
    __syncthreads();
    #pragma unroll
    for (int i = 0; i < 4; ++i) {
      const char* gA = A8 + (size_t)arow[i] * D_ + kt + (gch_ << 4);
      const char* gB = B8 + (size_t)brow[i] * D_ + kt + (gch_ << 4);
      __builtin_amdgcn_global_load_lds(
          (const __attribute__((address_space(1))) void*)gA,
          (__attribute__((address_space(3))) void*)(As + wave * 4096 + i * 1024), 16, 0, 0);
      __builtin_amdgcn_global_load_lds(
          (const __attribute__((address_space(1))) void*)gB,
          (__attribute__((address_space(3))) void*)(Bs + wave * 4096 + i * 1024), 16, 0, 0);
    }
    __syncthreads();
    #pragma unroll
    for (int kh = 0; kh < 2; ++kh) {
      i32x8 a0 = mx_frag(As, wm * 64 +  0 + l32, kh, sel);
      i32x8 a1 = mx_frag(As, wm * 64 + 32 + l32, kh, sel);
      i32x8 b0 = mx_frag(Bs, wn * 64 +  0 + l32, kh, sel);
      i32x8 b1 = mx_frag(Bs, wn * 64 + 32 + l32, kh, sel);
      acc[0][0] = __builtin_amdgcn_mfma_scale_f32_32x32x64_f8f6f4(a0, b0, acc[0][0], 0, 0, 0, 121, 0, 121);
      acc[0][1] = __builtin_amdgcn_mfma_scale_f32_32x32x64_f8f6f4(a0, b1, acc[0][1], 0, 0, 0, 121, 0, 121);
      acc[1][0] = __builtin_amdgcn_mfma_scale_f32_32x32x64_f8f6f4(a1, b0, acc[1][0], 0, 0, 0, 121, 0, 121);
      acc[1][1] = __builtin_amdgcn_mfma_scale_f32_32x32x64_f8f6f4(a1, b1, acc[1][1], 0, 0, 0, 121, 0, 121);
    }
  }

  // ---- epilogue 1: exp -> bf16 tile in reused LDS, 16B-chunk XOR swizzle ----------
  __syncthreads();   // all waves done reading As/Bs
  unsigned short* tile = (unsigned short*)smem;
  #pragma unroll
  for (int mt = 0; mt < 2; ++mt) {
    #pragma unroll
    for (int nt = 0; nt < 2; ++nt) {
      const int col = wn * 64 + nt * 32 + l32;
      const int cc = col >> 3, cl = col & 7;
      #pragma unroll
      for (int r = 0; r < 16; ++r) {
        const int row = wm * 64 + mt * 32 + (r & 3) + 8 * (r >> 2) + 4 * sel;
        const float v = __expf(sbeta[row] * acc[mt][nt][r]);
        tile[row * 128 + (((cc ^ (row & 7)) << 3) | cl)] = f2bf(v);
      }
    }
  }
  __syncthreads();

  // ---- epilogue 2: run sums = P @ E via bf16 MFMA; wave w owns rows w*32..+31 -----
  {
    const int quad = lane >> 4, l16 = lane & 15;
    const int rowb = wave * 32;
    f32x4 racc[2];
    racc[0] = (f32x4)0.f; racc[1] = (f32x4)0.f;
    #pragma unroll
    for (int kc = 0; kc < 4; ++kc) {
      const bf16x8 bfrag = *(const bf16x8*)(Es + l16 * 136 + kc * 32 + quad * 8);
      #pragma unroll
      for (int rg = 0; rg < 2; ++rg) {
        const int row = rowb + rg * 16 + l16;
        const int kch = kc * 4 + quad;
        const bf16x8 afrag = *(const bf16x8*)(tile + row * 128 + ((kch ^ (row & 7)) << 3));
        racc[rg] = __builtin_amdgcn_mfma_f32_16x16x32_bf16(afrag, bfrag, racc[rg], 0, 0, 0);
      }
    }
    const int tb = (nstart >> 7) * 16;
    #pragma unroll
    for (int rg = 0; rg < 2; ++rg) {
      #pragma unroll
      for (int r = 0; r < 4; ++r) {
        const int row = rowb + rg * 16 + quad * 4 + r;
        partials[(size_t)(rstart + row) * RSTRIDE + tb + l16] = racc[rg][r];
      }
    }
  }

  // ---- epilogue 3: last tile-block per rstart reduces partials -> out -------------
  __threadfence();                          // release: publish partials device-wide
  __syncthreads();                          // all threads' stores + fences done
  if (tid == 0) islast = (atomicAdd(&done[blockIdx.x], 1) == (int)gridDim.y - 1);
  __syncthreads();
  if (!islast) return;
  __threadfence();                          // acquire: see other blocks' partials

  int* sls = (int*)smem;                    // reuse tile region (done with it)
  for (int i = tid; i <= C_; i += 256) sls[i] = labstart[i];
  __syncthreads();
  const float sc = ps[0];
  for (int r = 0; r < 128; ++r) {
    const int row = rstart + r;
    const float a = out[(size_t)B_ * C_ + row];          // alpha
    const float* prow = partials + (size_t)row * RSTRIDE;
    for (int lab = tid; lab < C_; lab += 256) {
      float c = 0.f;
      for (int j = sls[lab]; j < sls[lab + 1]; ++j) c += prow[j];  // empty slots = 0
      const size_t oi = (size_t)row * C_ + lab;
      out[oi] = ((1.f - a) * z[oi] + a * c) * sc;
    }
  }
}

extern "C" void kernel_launch(void* const* d_in, const int* in_sizes, int n_in,
                              void* d_out, int out_size, void* d_ws, size_t ws_size,
                              hipStream_t stream) {
  const float* q          = (const float*)d_in[0];
  const float* z          = (const float*)d_in[1];
  const float* keys       = (const float*)d_in[2];
  const float* values     = (const float*)d_in[3];
  const float* fc1_w      = (const float*)d_in[4];
  const float* fc1_b      = (const float*)d_in[5];
  const float* fc2_w      = (const float*)d_in[6];
  const float* fc2_b      = (const float*)d_in[7];
  const float* post_scale = (const float*)d_in[8];
  float* out = (float*)d_out;

  // ws layout (byte offsets)
  char* ws = (char*)d_ws;
  short* qb        = (short*)(ws);                 //  8,388,608
  char*  q8        = (char*) (ws +  8388608);      //  4,194,304
  char*  keys8     = (char*) (ws + 12582912);      // 16,384,000
  short* fc1b      = (short*)(ws + 28966912);      //    524,288
  int*   labels    = (int*)  (ws + 29491200);      //     64,000
  int*   sortidx   = (int*)  (ws + 33761792);      //     64,000
  int*   runid     = (int*)  (ws + 33889792);      //     64,016
  int*   labstart  = (int*)  (ws + 33953808);      //      4,096
  int*   done      = (int*)  (ws + 33957904);      //        128 (32 ints)
  float* partials  = (float*)(ws + 33959936);      // 33,554,432 (B_ x RSTRIDE f32)

  float* alpha = out + (size_t)B_ * C_;   // alpha/beta written directly to output tail
  float* beta  = alpha + B_;

  hipMemsetAsync(done, 0, 128, stream);

  prep_kernel<<<CONVB + LBLK, 256, 0, stream>>>(
      (const float4*)q, (const float4*)keys, (const float4*)fc1_w, values,
      (ushort4*)qb, (int*)q8, (int*)keys8, (ushort4*)fc1b, labels);

  midpipe_kernel<<<B_ / 32 + 1, 1024, 0, stream>>>(
      qb, fc1b, fc1_b, fc2_w, fc2_b, alpha, labels, sortidx, runid, labstart);

  mxgemm_kernel<<<dim3(B_ / 128, NS_ / 128), 256, 0, stream>>>(
      q8, keys8, beta, partials, sortidx, runid,
      labstart, z, post_scale, out, done);
}

// Round 12
// 313.363 us; speedup vs baseline: 5.6442x; 5.6442x over previous
//
#include <hip/hip_runtime.h>
#include <hip/hip_bf16.h>
#include <stdint.h>

#define B_  4096
#define D_  1024
#define NS_ 16000
#define C_  1000
#define H_  256
#define LBLK 4000    // label-extraction blocks (4 waves/block, after conversions)
#define QCB  1024    // q conversion blocks   (1024*1024 float4 = exact)
#define KCB  4000    // keys conversion blocks (4000*1024 float4 = exact)
#define FCB  64      // fc1 conversion blocks  (64*1024 float4 = exact)
#define CONVB (QCB + KCB + FCB)
#define RSTRIDE 2048 // padded run stride (R = 125 tiles * 16 slots = 2000)

typedef __attribute__((ext_vector_type(8))) short bf16x8;
typedef __attribute__((ext_vector_type(4))) float f32x4;
typedef __attribute__((ext_vector_type(16))) float f32x16;
typedef __attribute__((ext_vector_type(8))) int i32x8;

__device__ __forceinline__ unsigned short f2bf(float f) {
  union { float f; unsigned u; } v; v.f = f;
  unsigned u = v.u;
  u += 0x7FFF + ((u >> 16) & 1);   // round-to-nearest-even
  return (unsigned short)(u >> 16);
}

__device__ __forceinline__ float bf2f(unsigned short h) {
  union { unsigned u; float f; } v; v.u = ((unsigned)h) << 16;
  return v.f;
}

// ---------------- fused prep: fp32 -> bf16/fp8 conversion (first), labels (last) ----
__global__ void prep_kernel(const float4* __restrict__ q, const float4* __restrict__ keys,
                            const float4* __restrict__ fc1, const float* __restrict__ values,
                            ushort4* __restrict__ qb, int* __restrict__ q8,
                            int* __restrict__ keys8, ushort4* __restrict__ fc1b,
                            int* __restrict__ labels) {
  const int bid = blockIdx.x;
  if (bid < QCB) {                                   // q -> qb (bf16) + q8 (fp8 x64)
    const size_t i0 = (size_t)bid * 1024 + threadIdx.x;
    #pragma unroll
    for (int k = 0; k < 4; ++k) {
      const size_t i = i0 + k * 256;
      float4 v = q[i];
      ushort4 r; r.x = f2bf(v.x); r.y = f2bf(v.y); r.z = f2bf(v.z); r.w = f2bf(v.w);
      qb[i] = r;
      int p = __builtin_amdgcn_cvt_pk_fp8_f32(v.x * 64.f, v.y * 64.f, 0, false);
      p     = __builtin_amdgcn_cvt_pk_fp8_f32(v.z * 64.f, v.w * 64.f, p, true);
      q8[i] = p;
    }
    return;
  }
  if (bid < QCB + KCB) {                             // keys -> keys8 (fp8 x64)
    const size_t i0 = (size_t)(bid - QCB) * 1024 + threadIdx.x;
    #pragma unroll
    for (int k = 0; k < 4; ++k) {
      const size_t i = i0 + k * 256;
      float4 v = keys[i];
      int p = __builtin_amdgcn_cvt_pk_fp8_f32(v.x * 64.f, v.y * 64.f, 0, false);
      p     = __builtin_amdgcn_cvt_pk_fp8_f32(v.z * 64.f, v.w * 64.f, p, true);
      keys8[i] = p;
    }
    return;
  }
  if (bid < CONVB) {                                 // fc1 -> fc1b (bf16)
    const size_t i0 = (size_t)(bid - QCB - KCB) * 1024 + threadIdx.x;
    #pragma unroll
    for (int k = 0; k < 4; ++k) {
      const size_t i = i0 + k * 256;
      float4 v = fc1[i];
      ushort4 r; r.x = f2bf(v.x); r.y = f2bf(v.y); r.z = f2bf(v.z); r.w = f2bf(v.w);
      fc1b[i] = r;
    }
    return;
  }
  // label extraction: wave per support row, early exit on one-hot hit
  const int s = (bid - CONVB) * 4 + (threadIdx.x >> 6);
  const int lane = threadIdx.x & 63;
  const float4* row = (const float4*)(values + (size_t)s * C_);
  int lab = -1;
  for (int j = lane; j < C_ / 4; j += 64) {
    float4 v = row[j];
    if (v.x > 0.5f) lab = j * 4 + 0;
    if (v.y > 0.5f) lab = j * 4 + 1;
    if (v.z > 0.5f) lab = j * 4 + 2;
    if (v.w > 0.5f) lab = j * 4 + 3;
    if (__ballot(lab >= 0)) break;     // one-hot: whole wave exits once found
  }
  if (lab >= 0) labels[s] = lab;
}

// ---------------- midpipe: gemmgate (blocks 0..127) ∥ sortpipe (block 128) ----------
// sortpipe builds hist from labels via LDS atomics (no memset / global hist).
union MidShared {
  struct {
    short As[32 * 64];                 //  4 KB
    short Bs[256 * 64];                // 32 KB
    float gred[4][32][2];              //  1 KB
  } g;
  struct {
    int sscan[1024];                   //  4 KB
    int sboff[C_ + 1];
    int scnt[C_];
    unsigned short slab[NS_];          // 32 KB
    int stile[NS_ / 128];
  } s;
};

__global__ __launch_bounds__(1024) void midpipe_kernel(
    const short* __restrict__ A, const short* __restrict__ Bm,
    const float* __restrict__ bias, const float* __restrict__ fc2_w,
    const float* __restrict__ fc2_b, float* __restrict__ ab,
    const int* __restrict__ labels,
    int* __restrict__ sortidx, int* __restrict__ runid, int* __restrict__ labstart)
{
  __shared__ MidShared u;
  const int tid = threadIdx.x;

  if (blockIdx.x < B_ / 32) {
    // ---- gemmgate: fused fc1 GEMM + gate, threads 0..255 active ----
    short* As = u.g.As;
    short* Bs = u.g.Bs;
    const bool act = tid < 256;
    const int wave = (tid >> 6) & 3, lane = tid & 63;
    const int quad = lane >> 4, l16 = lane & 15;
    const int wn = wave;                      // wave owns cols wn*64..+63
    const int rstart = blockIdx.x * 32;

    f32x4 acc[2][4];
    #pragma unroll
    for (int i = 0; i < 2; ++i)
      #pragma unroll
      for (int j = 0; j < 4; ++j) acc[i][j] = (f32x4)0.f;

    const int r_  = (lane >> 3);             // 0..7 (row within 8-row chunk)
    const int kc_ = ((lane & 7) ^ r_) * 8;   // swizzled 16B k-chunk element offset

    for (int kt = 0; kt < D_; kt += 64) {
      __syncthreads();
      if (act) {
        {   // A: 32 rows = 4 groups of 1KB, one per wave
          const int row = wave * 8 + r_;
          const short* gA = A + (size_t)(rstart + row) * D_ + kt + kc_;
          __builtin_amdgcn_global_load_lds(
              (const __attribute__((address_space(1))) void*)gA,
              (__attribute__((address_space(3))) void*)(As + wave * 512), 16, 0, 0);
        }
        #pragma unroll
        for (int i = 0; i < 8; ++i) {        // B: 256 rows = 32 groups
          const int g = i * 4 + wave;
          const int row = g * 8 + r_;
          const short* gB = Bm + (size_t)row * D_ + kt + kc_;
          __builtin_amdgcn_global_load_lds(
              (const __attribute__((address_space(1))) void*)gB,
              (__attribute__((address_space(3))) void*)(Bs + g * 512), 16, 0, 0);
        }
      }
      __syncthreads();
      if (act) {
        #pragma unroll
        for (int ks = 0; ks < 64; ks += 32) {
          bf16x8 af[2], bfr[4];
          const int kb = (ks >> 3) + quad;
          #pragma unroll
          for (int mt = 0; mt < 2; ++mt) {
            const int row = mt * 16 + l16;
            af[mt] = *(const bf16x8*)(As + row * 64 + ((kb ^ (row & 7)) << 3));
          }
          #pragma unroll
          for (int nt = 0; nt < 4; ++nt) {
            const int row = wn * 64 + nt * 16 + l16;
            bfr[nt] = *(const bf16x8*)(Bs + row * 64 + ((kb ^ (row & 7)) << 3));
          }
          #pragma unroll
          for (int mt = 0; mt < 2; ++mt)
            #pragma unroll
            for (int nt = 0; nt < 4; ++nt)
              acc[mt][nt] = __builtin_amdgcn_mfma_f32_16x16x32_bf16(af[mt], bfr[nt], acc[mt][nt], 0, 0, 0);
        }
      }
    }

    if (act) {
      // gate partials: g = sum_col relu(acc+bias)*fc2_w[.,col]
      float g0p[2][4], g1p[2][4];
      #pragma unroll
      for (int mt = 0; mt < 2; ++mt)
        #pragma unroll
        for (int r = 0; r < 4; ++r) { g0p[mt][r] = 0.f; g1p[mt][r] = 0.f; }
      #pragma unroll
      for (int nt = 0; nt < 4; ++nt) {
        const int col = wn * 64 + nt * 16 + l16;
        const float bv = bias[col];
        const float w0 = fc2_w[col], w1 = fc2_w[H_ + col];
        #pragma unroll
        for (int mt = 0; mt < 2; ++mt)
          #pragma unroll
          for (int r = 0; r < 4; ++r) {
            float xv = acc[mt][nt][r] + bv;
            xv = xv > 0.f ? xv : 0.f;
            g0p[mt][r] += xv * w0;
            g1p[mt][r] += xv * w1;
          }
      }
      #pragma unroll
      for (int mt = 0; mt < 2; ++mt)
        #pragma unroll
        for (int r = 0; r < 4; ++r) {
          float a0 = g0p[mt][r], a1 = g1p[mt][r];
          #pragma unroll
          for (int off = 8; off > 0; off >>= 1) {   // reduce over l16 within quad
            a0 += __shfl_xor(a0, off);
            a1 += __shfl_xor(a1, off);
          }
          if (l16 == 0) {
            const int row = mt * 16 + quad * 4 + r;
            u.g.gred[wave][row][0] = a0;
            u.g.gred[wave][row][1] = a1;
          }
        }
    }
    __syncthreads();
    if (tid < 32) {
      float g0 = u.g.gred[0][tid][0] + u.g.gred[1][tid][0] + u.g.gred[2][tid][0] +
                 u.g.gred[3][tid][0] + fc2_b[0];
      float g1 = u.g.gred[0][tid][1] + u.g.gred[1][tid][1] + u.g.gred[2][tid][1] +
                 u.g.gred[3][tid][1] + fc2_b[1];
      ab[rstart + tid]      = 1.f / (1.f + __expf(-g0));                              // alpha
      ab[B_ + rstart + tid] = fmaxf(g1, 0.f) + log1pf(__expf(-fabsf(g1))) + 0.001f;   // beta
    }
    return;
  }

  // ---- sortpipe: hist + scan + scatter + runid + labstart (1 block, 1024 thr) ----
  const int t = tid;
  if (t < C_) u.s.scnt[t] = 0;
  __syncthreads();
  for (int s = t; s < NS_; s += 1024)
    atomicAdd(&u.s.scnt[labels[s]], 1);              // hist via LDS atomics
  __syncthreads();
  int v = (t < C_) ? u.s.scnt[t] : 0;
  u.s.sscan[t] = v;
  __syncthreads();
  if (t < C_) u.s.scnt[t] = 0;                       // re-zero for scatter
  for (int off = 1; off < 1024; off <<= 1) {
    int w = (t >= off) ? u.s.sscan[t - off] : 0;
    __syncthreads(); u.s.sscan[t] += w; __syncthreads();
  }
  if (t == 0) u.s.sboff[0] = 0;
  if (t < C_) u.s.sboff[t + 1] = u.s.sscan[t];
  __syncthreads();

  for (int s = t; s < NS_; s += 1024) {
    const int lab = labels[s];
    const int pos = u.s.sboff[lab] + atomicAdd(&u.s.scnt[lab], 1);
    sortidx[pos] = s;
    u.s.slab[pos] = (unsigned short)lab;
  }
  __syncthreads();

  // runid: slot = (c>>7)*16 + label-rank-within-tile (rank < 16 whp)
  const int c0 = t * 16;
  int flags[16]; int cnt = 0;
  if (c0 < NS_) {
    int prev = (c0 == 0) ? u.s.slab[0] : u.s.slab[c0 - 1];
    #pragma unroll
    for (int i = 0; i < 16; ++i) {
      const int l = u.s.slab[c0 + i];
      const int f = ((c0 + i) != 0) && (l != prev);
      flags[i] = f; cnt += f; prev = l;
    }
  }
  u.s.sscan[t] = cnt; __syncthreads();
  for (int off = 1; off < 1024; off <<= 1) {
    int w = (t >= off) ? u.s.sscan[t - off] : 0;
    __syncthreads(); u.s.sscan[t] += w; __syncthreads();
  }
  if (c0 < NS_ && (t & 7) == 0) u.s.stile[t >> 3] = (u.s.sscan[t] - cnt) + flags[0];
  __syncthreads();
  if (c0 < NS_) {
    int run = u.s.sscan[t] - cnt;
    const int base = (c0 >> 7) * 16 - u.s.stile[c0 >> 7];
    #pragma unroll
    for (int i = 0; i < 16; ++i) {
      run += flags[i];
      runid[c0 + i] = base + run;
    }
  }
  if (t == 0) runid[NS_] = (NS_ >> 7) * 16;   // 2000
  __threadfence();
  __syncthreads();
  if (t <= C_) labstart[t] = runid[u.s.sboff[t]];
}

// ---------------- MX-fp8 128x128 GEMM, fused exp + MFMA segmented label-sum ---------
// r8-proven structure (A+B staged via global_load_lds); 4 blocks/CU occupancy.
__device__ __forceinline__ i32x8 mx_frag(const char* base, int lrow, int kh, int sel) {
  const int c0 = kh * 4 + sel * 2;
  const int s = lrow & 7;
  const int4 lo = *(const int4*)(base + lrow * 128 + (((c0    ) ^ s) << 4));
  const int4 hi = *(const int4*)(base + lrow * 128 + (((c0 + 1) ^ s) << 4));
  i32x8 f;
  f[0] = lo.x; f[1] = lo.y; f[2] = lo.z; f[3] = lo.w;
  f[4] = hi.x; f[5] = hi.y; f[6] = hi.z; f[7] = hi.w;
  return f;
}

__global__ __launch_bounds__(256, 4) void mxgemm_kernel(
    const char* __restrict__ A8, const char* __restrict__ B8,
    const float* __restrict__ beta, float* __restrict__ partials,
    const int* __restrict__ sortidx, const int* __restrict__ runid)
{
  __shared__ __align__(16) char smem[32768];   // As|Bs in K-loop; bf16 tile in epilogue
  __shared__ float sbeta[128];
  __shared__ __align__(16) unsigned short Es[16 * 136];  // E[slot][k], stride 136
  char* As = smem;
  char* Bs = smem + 16384;

  const int tid  = threadIdx.x;
  const int wave = tid >> 6, lane = tid & 63;
  const int sel  = lane >> 5, l32 = lane & 31;
  const int wm = wave >> 1, wn = wave & 1;     // 2x2 wave grid, 64x64 per wave
  const int rstart = blockIdx.x * 128;         // x fastest: blocks share nstart window
  const int nstart = blockIdx.y * 128;

  // build E: zero, then one-hot 1.0 at (slot = local label rank, k = col-in-tile)
  for (int i = tid; i < (16 * 136) / 2; i += 256) ((int*)Es)[i] = 0;
  if (tid < 128) sbeta[tid] = beta[rstart + tid];
  __syncthreads();
  if (tid < 128) Es[(runid[nstart + tid] & 15) * 136 + tid] = 0x3F80;  // 1.0 bf16

  // staging geometry: slot s = wave*256 + i*64 + lane; row = s>>3, chunk c = s&7
  const int srow_ = (lane >> 3);           // row offset within 8-row group
  const int gch_  = (lane & 7) ^ srow_;    // swizzled source chunk (row&7 == lane>>3)

  int arow[4], brow[4];
  #pragma unroll
  for (int i = 0; i < 4; ++i) {
    const int row = wave * 32 + i * 8 + srow_;
    arow[i] = rstart + row;
    brow[i] = sortidx[nstart + row];
  }

  f32x16 acc[2][2];
  #pragma unroll
  for (int i = 0; i < 2; ++i)
    #pragma unroll
    for (int j = 0; j < 2; ++j) acc[i][j] = (f32x16)0.f;

  for (int kt = 0; kt < D_; kt += 128) {
    __syncthreads();
    #pragma unroll
    for (int i = 0; i < 4; ++i) {
      const char* gA = A8 + (size_t)arow[i] * D_ + kt + (gch_ << 4);
      const char* gB = B8 + (size_t)brow[i] * D_ + kt + (gch_ << 4);
      __builtin_amdgcn_global_load_lds(
          (const __attribute__((address_space(1))) void*)gA,
          (__attribute__((address_space(3))) void*)(As + wave * 4096 + i * 1024), 16, 0, 0);
      __builtin_amdgcn_global_load_lds(
          (const __attribute__((address_space(1))) void*)gB,
          (__attribute__((address_space(3))) void*)(Bs + wave * 4096 + i * 1024), 16, 0, 0);
    }
    __syncthreads();
    #pragma unroll
    for (int kh = 0; kh < 2; ++kh) {
      i32x8 a0 = mx_frag(As, wm * 64 +  0 + l32, kh, sel);
      i32x8 a1 = mx_frag(As, wm * 64 + 32 + l32, kh, sel);
      i32x8 b0 = mx_frag(Bs, wn * 64 +  0 + l32, kh, sel);
      i32x8 b1 = mx_frag(Bs, wn * 64 + 32 + l32, kh, sel);
      acc[0][0] = __builtin_amdgcn_mfma_scale_f32_32x32x64_f8f6f4(a0, b0, acc[0][0], 0, 0, 0, 121, 0, 121);
      acc[0][1] = __builtin_amdgcn_mfma_scale_f32_32x32x64_f8f6f4(a0, b1, acc[0][1], 0, 0, 0, 121, 0, 121);
      acc[1][0] = __builtin_amdgcn_mfma_scale_f32_32x32x64_f8f6f4(a1, b0, acc[1][0], 0, 0, 0, 121, 0, 121);
      acc[1][1] = __builtin_amdgcn_mfma_scale_f32_32x32x64_f8f6f4(a1, b1, acc[1][1], 0, 0, 0, 121, 0, 121);
    }
  }

  // ---- epilogue 1: exp -> bf16 tile in reused LDS, 16B-chunk XOR swizzle ----------
  __syncthreads();   // all waves done reading As/Bs
  unsigned short* tile = (unsigned short*)smem;
  #pragma unroll
  for (int mt = 0; mt < 2; ++mt) {
    #pragma unroll
    for (int nt = 0; nt < 2; ++nt) {
      const int col = wn * 64 + nt * 32 + l32;
      const int cc = col >> 3, cl = col & 7;
      #pragma unroll
      for (int r = 0; r < 16; ++r) {
        const int row = wm * 64 + mt * 32 + (r & 3) + 8 * (r >> 2) + 4 * sel;
        const float v = __expf(sbeta[row] * acc[mt][nt][r]);
        tile[row * 128 + (((cc ^ (row & 7)) << 3) | cl)] = f2bf(v);
      }
    }
  }
  __syncthreads();

  // ---- epilogue 2: run sums = P @ E via bf16 MFMA; wave w owns rows w*32..+31 -----
  {
    const int quad = lane >> 4, l16 = lane & 15;
    const int rowb = wave * 32;
    f32x4 racc[2];
    racc[0] = (f32x4)0.f; racc[1] = (f32x4)0.f;
    #pragma unroll
    for (int kc = 0; kc < 4; ++kc) {
      const bf16x8 bfrag = *(const bf16x8*)(Es + l16 * 136 + kc * 32 + quad * 8);
      #pragma unroll
      for (int rg = 0; rg < 2; ++rg) {
        const int row = rowb + rg * 16 + l16;
        const int kch = kc * 4 + quad;
        const bf16x8 afrag = *(const bf16x8*)(tile + row * 128 + ((kch ^ (row & 7)) << 3));
        racc[rg] = __builtin_amdgcn_mfma_f32_16x16x32_bf16(afrag, bfrag, racc[rg], 0, 0, 0);
      }
    }
    const int tb = (nstart >> 7) * 16;
    #pragma unroll
    for (int rg = 0; rg < 2; ++rg) {
      #pragma unroll
      for (int r = 0; r < 4; ++r) {
        const int row = rowb + rg * 16 + quad * 4 + r;
        partials[(size_t)(rstart + row) * RSTRIDE + tb + l16] = racc[rg][r];
      }
    }
  }
}

// ---------------- reduce: c[b][lab] = sum slots; out = ((1-a)z + a*c)*ps ------------
__global__ __launch_bounds__(256) void reduce_kernel(
    const float* __restrict__ partials, const int* __restrict__ labstart,
    const float* __restrict__ z, const float* __restrict__ ps, float* __restrict__ out) {
  __shared__ __align__(16) float sp[RSTRIDE];
  __shared__ int sls[C_ + 1];
  const int b = blockIdx.x;
  const int t = threadIdx.x;
  for (int i = t; i <= C_; i += 256) sls[i] = labstart[i];
  const float4* p4 = (const float4*)(partials + (size_t)b * RSTRIDE);
  float4* s4 = (float4*)sp;
  for (int i = t; i < RSTRIDE / 4; i += 256) s4[i] = p4[i];
  __syncthreads();
  const float a  = out[(size_t)B_ * C_ + b];   // alpha (midpipe ran earlier)
  const float sc = ps[0];
  for (int lab = t; lab < C_; lab += 256) {
    float c = 0.f;
    for (int j = sls[lab]; j < sls[lab + 1]; ++j) c += sp[j];   // empty slots are 0
    const size_t oi = (size_t)b * C_ + lab;
    out[oi] = ((1.f - a) * z[oi] + a * c) * sc;
  }
}

extern "C" void kernel_launch(void* const* d_in, const int* in_sizes, int n_in,
                              void* d_out, int out_size, void* d_ws, size_t ws_size,
                              hipStream_t stream) {
  const float* q          = (const float*)d_in[0];
  const float* z          = (const float*)d_in[1];
  const float* keys       = (const float*)d_in[2];
  const float* values     = (const float*)d_in[3];
  const float* fc1_w      = (const float*)d_in[4];
  const float* fc1_b      = (const float*)d_in[5];
  const float* fc2_w      = (const float*)d_in[6];
  const float* fc2_b      = (const float*)d_in[7];
  const float* post_scale = (const float*)d_in[8];
  float* out = (float*)d_out;

  // ws layout (byte offsets)
  char* ws = (char*)d_ws;
  short* qb        = (short*)(ws);                 //  8,388,608
  char*  q8        = (char*) (ws +  8388608);      //  4,194,304
  char*  keys8     = (char*) (ws + 12582912);      // 16,384,000
  short* fc1b      = (short*)(ws + 28966912);      //    524,288
  int*   labels    = (int*)  (ws + 29491200);      //     64,000
  int*   sortidx   = (int*)  (ws + 33761792);      //     64,000
  int*   runid     = (int*)  (ws + 33889792);      //     64,016
  int*   labstart  = (int*)  (ws + 33953808);      //      4,096
  float* partials  = (float*)(ws + 33959936);      // 33,554,432 (B_ x RSTRIDE f32)

  float* alpha = out + (size_t)B_ * C_;   // alpha/beta written directly to output tail
  float* beta  = alpha + B_;

  prep_kernel<<<CONVB + LBLK, 256, 0, stream>>>(
      (const float4*)q, (const float4*)keys, (const float4*)fc1_w, values,
      (ushort4*)qb, (int*)q8, (int*)keys8, (ushort4*)fc1b, labels);

  midpipe_kernel<<<B_ / 32 + 1, 1024, 0, stream>>>(
      qb, fc1b, fc1_b, fc2_w, fc2_b, alpha, labels, sortidx, runid, labstart);

  mxgemm_kernel<<<dim3(B_ / 128, NS_ / 128), 256, 0, stream>>>(
      q8, keys8, beta, partials, sortidx, runid);

  reduce_kernel<<<B_, 256, 0, stream>>>(partials, labstart, z, post_scale, out);
}